// Round 1
// baseline (268.290 us; speedup 1.0000x reference)
//
#include <hip/hip_runtime.h>
#include <math.h>

#define C_OLD 23
#define G 10
#define BVAL 8
#define NVAL 262144                  // 2^18 rows per b
#define BLOCK 256
#define WAVES (BLOCK / 64)           // 4
#define ROWS_PER_CHUNK 64            // rows per wave per chunk (1 row/lane)
#define CHUNKS 4                     // chunks per wave -> 256 rows/wave, 1024/block
#define BLOCKS_PER_B 256             // 256 * 1024 = 262144 rows = N
#define NBLOCKS (BVAL * BLOCKS_PER_B)          // 2048
#define CHUNK_FLOATS (ROWS_PER_CHUNK * C_OLD)  // 1472 floats = 5888 B per wave
#define CHUNK_VEC4 (CHUNK_FLOATS / 4)          // 368 float4 per chunk
#define REM (CHUNK_VEC4 - 5 * 64)              // 48

struct Frag { float4 r0, r1, r2, r3, r4, r5; };

__device__ __forceinline__ Frag load_chunk(const float4* __restrict__ s, int lane) {
    Frag f;
    f.r0 = s[lane];        f.r1 = s[lane + 64];   f.r2 = s[lane + 128];
    f.r3 = s[lane + 192];  f.r4 = s[lane + 256];
    if (lane < REM) f.r5 = s[lane + 320];
    return f;
}

__device__ __forceinline__ void store_chunk(float4* d, int lane, const Frag& f) {
    d[lane] = f.r0;        d[lane + 64] = f.r1;   d[lane + 128] = f.r2;
    d[lane + 192] = f.r3;  d[lane + 256] = f.r4;
    if (lane < REM) d[lane + 320] = f.r5;
}

__device__ __forceinline__ void accum_row(const float* __restrict__ row, float* acc) {
    float s0 = row[0] + row[1];
    float s1 = row[2] + row[3];
    float s2 = row[4] + row[5] + row[6];
    float s3 = row[7] + row[8];
    float s4 = row[9] + row[10] + row[11];
    float s5 = row[12] + row[13];
    float s6 = row[14] + row[15] + row[16];
    float s7 = row[17] + row[18];
    float s8 = row[19] + row[20];
    float s9 = row[21] + row[22];
    float tot = ((s0 + s1) + (s2 + s3)) + ((s4 + s5) + (s6 + s7)) + (s8 + s9);
    float inv = 1.0f / tot;
    acc[0] += s0 * inv; acc[1] += s1 * inv; acc[2] += s2 * inv;
    acc[3] += s3 * inv; acc[4] += s4 * inv; acc[5] += s5 * inv;
    acc[6] += s6 * inv; acc[7] += s7 * inv; acc[8] += s8 * inv;
    acc[9] += s9 * inv;
}

// ws layout: part[(b*G + g) * BLOCKS_PER_B + blk]  -> 80*256 floats = 81920 B
__global__ __launch_bounds__(BLOCK) void group_prob_partial_kernel(
        const float* __restrict__ in, float* __restrict__ part) {
    __shared__ float lds[WAVES][CHUNK_FLOATS];   // wave-private: no barriers in loop
    __shared__ float wpart[WAVES][G];

    const int tid  = threadIdx.x;
    const int wave = tid >> 6;
    const int lane = tid & 63;
    const int b    = blockIdx.x >> 8;                 // BLOCKS_PER_B == 256
    const int blk  = blockIdx.x & (BLOCKS_PER_B - 1);

    const long long rowBase = (long long)b * NVAL
                            + (long long)blk * (ROWS_PER_CHUNK * CHUNKS * WAVES)
                            + (long long)wave * (ROWS_PER_CHUNK * CHUNKS);
    const float4* __restrict__ src0 = (const float4*)(in + rowBase * C_OLD);

    float4* dstv = (float4*)lds[wave];
    const float* row = lds[wave] + lane * C_OLD;      // stride 23: 2-way alias, free

    float acc[G];
    #pragma unroll
    for (int g = 0; g < G; ++g) acc[g] = 0.0f;

    // ---- distance-2 prefetch: two register sets, single wave-private buffer.
    // Each ds_write waits on loads issued a FULL chunk earlier (vmcnt(6)-style
    // fine-grained wait; no barriers anywhere to force a vmcnt(0) drain).
    // Same-wave DS pipe is in-order: write-after-read needs no sync. ----
    Frag A = load_chunk(src0, lane);                   // chunk 0
    Frag B = load_chunk(src0 + CHUNK_VEC4, lane);      // chunk 1
    store_chunk(dstv, lane, A);                        // waits on A only

    #pragma unroll
    for (int cc = 0; cc < CHUNKS; cc += 2) {
        accum_row(row, acc);                           // chunk cc
        if (cc + 2 < CHUNKS) A = load_chunk(src0 + (cc + 2) * CHUNK_VEC4, lane);
        store_chunk(dstv, lane, B);                    // chunk cc+1 -> LDS (old loads)
        accum_row(row, acc);                           // chunk cc+1
        if (cc + 3 < CHUNKS) B = load_chunk(src0 + (cc + 3) * CHUNK_VEC4, lane);
        if (cc + 2 < CHUNKS) store_chunk(dstv, lane, A);   // chunk cc+2 -> LDS
    }

    // ---- wave shuffle reduction (256 rows/wave), then cross-wave via LDS ----
    #pragma unroll
    for (int g = 0; g < G; ++g) {
        float v = acc[g];
        #pragma unroll
        for (int off = 32; off > 0; off >>= 1)
            v += __shfl_down(v, off, 64);
        acc[g] = v;
    }
    if (lane == 0) {
        #pragma unroll
        for (int g = 0; g < G; ++g) wpart[wave][g] = acc[g];
    }
    __syncthreads();
    if (tid < G) {
        float s = wpart[0][tid] + wpart[1][tid] + wpart[2][tid] + wpart[3][tid];
        part[((long long)b * G + tid) * BLOCKS_PER_B + blk] = s;
    }
}

__global__ void finalize_kernel(const float* __restrict__ part,
                                const float* __restrict__ tgt,
                                float* __restrict__ out) {
    __shared__ double red[128];
    const int t = threadIdx.x;
    double term = 0.0;
    if (t < BVAL * G) {
        const float4* p4 = (const float4*)(part + (long long)t * BLOCKS_PER_B);
        double s = 0.0;
        #pragma unroll 8
        for (int i = 0; i < BLOCKS_PER_B / 4; ++i) {
            float4 v = p4[i];
            s += (double)v.x + (double)v.y + (double)v.z + (double)v.w;
        }
        double avg = s / (double)NVAL;          // mean prob over N
        double tv  = (double)tgt[t];
        term = tv * (log(tv) - log(avg));
    }
    red[t] = term;
    __syncthreads();
    #pragma unroll
    for (int s = 64; s > 0; s >>= 1) {
        if (t < s) red[t] += red[t + s];
        __syncthreads();
    }
    if (t == 0) out[0] = (float)(red[0] / (double)(G * BVAL));
}

extern "C" void kernel_launch(void* const* d_in, const int* in_sizes, int n_in,
                              void* d_out, int out_size, void* d_ws, size_t ws_size,
                              hipStream_t stream) {
    const float* inputs  = (const float*)d_in[0];   // [8, 262144, 23] f32
    const float* targets = (const float*)d_in[1];   // [8, 10] f32
    float* out  = (float*)d_out;                    // scalar f32
    float* part = (float*)d_ws;                     // 80 * 256 floats

    group_prob_partial_kernel<<<NBLOCKS, BLOCK, 0, stream>>>(inputs, part);
    finalize_kernel<<<1, 128, 0, stream>>>(part, targets, out);
}